// Round 10
// baseline (220.792 us; speedup 1.0000x reference)
//
#include <hip/hip_runtime.h>
#include <hip/hip_bf16.h>

// B=4, T=2048, C=1024 single-head causal attention, fp32 in/out.
// R17: algebraic restructure. S = x(Wq^T Wk)x^T: G = Wk^T Wq (64-blk thin
// GEMM from transposed-cast weights), Y = xb@G^T (fat core fused with
// V = xb@Wv^T -> vT; 512 blocks = exactly 1 residency round), S = Y@xb^T.
// K never materialized (-15 GFLOP, -1/3 of the big-GEMM phase).
// pv_finish eliminated: split-K partials combine via scaled atomicAdd
// (2 commutative fp32 adds/element, replay-deterministic) into d_out
// rows >=1024, pre-zeroed in cast_all. All proven 2-phase cores.

typedef short bf16x8 __attribute__((ext_vector_type(8)));
typedef float f32x4  __attribute__((ext_vector_type(4)));

#define T_SEQ 2048
#define EMB   1024
#define NBAT  4

struct alignas(8) bh4 { __hip_bfloat16 a, b, c, d; };

__device__ __forceinline__ bh4 pack4(float x, float y, float z, float w) {
    bh4 o { __float2bfloat16(x), __float2bfloat16(y),
            __float2bfloat16(z), __float2bfloat16(w) };
    return o;
}

// ---------------------------------------------------------------- cast + zero
// grid 13856: [0,8192) x-cast | [8192,9216) Wv-cast | [9216,9728) WqT/WkT
// transpose-cast | [9728,9760) Lbuf zero | [9760,13856) d_out rows>=1024 zero.
__global__ void cast_all(const float* __restrict__ x,
                         const float* __restrict__ wq,
                         const float* __restrict__ wk,
                         const float* __restrict__ wv,
                         __hip_bfloat16* __restrict__ xb,
                         __hip_bfloat16* __restrict__ wqt,
                         __hip_bfloat16* __restrict__ wkt,
                         __hip_bfloat16* __restrict__ wvb,
                         float* __restrict__ Lbuf,
                         float* __restrict__ outbase) {
    __shared__ __hip_bfloat16 tile[64][65];
    const int bid = blockIdx.x;
    const int tid = threadIdx.x;
    if (bid < 8192) {
        int i = bid * 256 + tid;
        float4 v = reinterpret_cast<const float4*>(x)[i];
        reinterpret_cast<bh4*>(xb)[i] = pack4(v.x, v.y, v.z, v.w);
    } else if (bid < 9216) {
        int i = (bid - 8192) * 256 + tid;
        float4 v = reinterpret_cast<const float4*>(wv)[i];
        reinterpret_cast<bh4*>(wvb)[i] = pack4(v.x, v.y, v.z, v.w);
    } else if (bid < 9728) {
        const int k = bid - 9216;                 // 0..511
        const float* src = (k & 256) ? wk : wq;
        __hip_bfloat16* dst = (k & 256) ? wkt : wqt;
        const int t  = k & 255;
        const int r0 = (t >> 4) * 64;             // source row (d) tile
        const int c0 = (t & 15) * 64;             // source col (c) tile
        const int cc = tid & 63;
        const int r4 = tid >> 6;
        #pragma unroll
        for (int i = 0; i < 16; ++i) {
            int row = r4 + i * 4;
            tile[row][cc] = __float2bfloat16(src[(r0 + row) * 1024 + c0 + cc]);
        }
        __syncthreads();
        #pragma unroll
        for (int i = 0; i < 16; ++i) {
            int dr = r4 + i * 4;
            dst[(size_t)(c0 + dr) * 1024 + r0 + cc] = tile[cc][dr];
        }
    } else if (bid < 9760) {
        Lbuf[(bid - 9728) * 256 + tid] = 0.f;
    } else {
        const int g = bid - 9760;                 // 0..4095
        const int b = g >> 10;
        const int r = (g & 1023) + 1024;
        float4 z = make_float4(0.f, 0.f, 0.f, 0.f);
        reinterpret_cast<float4*>(outbase + (long)b * 2097152 + (long)r * 1024)[tid] = z;
    }
}

// ---------------------------------------------------------------- helpers
__device__ __forceinline__ void load_lds16(const void* g, void* l) {
    __builtin_amdgcn_global_load_lds(
        (const __attribute__((address_space(1))) void*)g,
        (__attribute__((address_space(3))) void*)l, 16, 0, 0);
}

// ================================================================ G core
// G[a,b] = sum_d Wk[d,a] Wq[d,b]  via core(A=WkT, B=WqT), thin 128x128.
// 64 blocks, K=1024, lda=ldb=ldc=1024. Plain bf16 store.
__global__ __launch_bounds__(256, 3) void g_gemm(
    const __hip_bfloat16* __restrict__ Wkt,
    const __hip_bfloat16* __restrict__ Wqt,
    __hip_bfloat16* __restrict__ G)
{
    const int rt = blockIdx.x >> 3;           // 0..7
    const int ct = blockIdx.x & 7;            // 0..7

    __shared__ short lsA[2][128 * 32];
    __shared__ short lsB[2][128 * 32];

    const int tid  = threadIdx.x;
    const int wave = tid >> 6;
    const int lane = tid & 63;
    const int wr   = (wave >> 1) * 64;
    const int wc   = (wave &  1) * 64;
    const int srow = wave * 32 + (lane >> 2);
    const int scol = ((lane & 3) ^ ((lane >> 3) & 3)) * 8;   // T2 swizzle
    const int frow = lane & 15;
    const int fk   = ((lane >> 4) ^ ((lane >> 1) & 3)) * 8;

    const short* A = (const short*)Wkt + (long)rt * 128 * 1024;
    const short* B = (const short*)Wqt + (long)ct * 128 * 1024;

    f32x4 acc[4][4] = {};

    for (int k0 = 0; k0 < 1024; k0 += 64) {
        const short* ga = A + (long)srow * 1024 + k0 + scol;
        const short* gb = B + (long)srow * 1024 + k0 + scol;
        load_lds16(gb,                   &lsB[0][(wave * 32) * 32]);
        load_lds16(gb + 16384,           &lsB[0][(wave * 32 + 16) * 32]);
        load_lds16(gb + 32,              &lsB[1][(wave * 32) * 32]);
        load_lds16(gb + 16384 + 32,      &lsB[1][(wave * 32 + 16) * 32]);
        load_lds16(ga,                   &lsA[0][(wave * 32) * 32]);
        load_lds16(ga + 16384,           &lsA[0][(wave * 32 + 16) * 32]);
        load_lds16(ga + 32,              &lsA[1][(wave * 32) * 32]);
        load_lds16(ga + 16384 + 32,      &lsA[1][(wave * 32 + 16) * 32]);
        __syncthreads();

        #pragma unroll
        for (int sub = 0; sub < 2; ++sub) {
            bf16x8 af[4], bfr[4];
            #pragma unroll
            for (int m = 0; m < 4; ++m)
                af[m] = *(const bf16x8*)&lsA[sub][(wr + m * 16 + frow) * 32 + fk];
            #pragma unroll
            for (int n = 0; n < 4; ++n)
                bfr[n] = *(const bf16x8*)&lsB[sub][(wc + n * 16 + frow) * 32 + fk];
            #pragma unroll
            for (int m = 0; m < 4; ++m)
                #pragma unroll
                for (int n = 0; n < 4; ++n)
                    acc[m][n] = __builtin_amdgcn_mfma_f32_16x16x32_bf16(
                        af[m], bfr[n], acc[m][n], 0, 0, 0);
        }
        __syncthreads();
    }

    const long crow0 = (long)rt * 128 + wr;
    const long ccol0 = (long)ct * 128 + wc;
    const int  orow  = (lane >> 4) * 4;
    const int  ocol  = lane & 15;
    #pragma unroll
    for (int m = 0; m < 4; ++m)
        #pragma unroll
        for (int n = 0; n < 4; ++n)
            #pragma unroll
            for (int r = 0; r < 4; ++r)
                G[(crow0 + m * 16 + orow + r) * 1024 + ccol0 + n * 16 + ocol] =
                    __float2bfloat16(acc[m][n][r]);
}

// ================================================================ Y|V core
// Fat 256x128, 4 waves, wave 128x64. 512 blocks = 8 XCD x 64 = 1 round.
// ct<8:  Y = xb @ G^T   -> Y[8192][1024]
// ct>=8: V = xb @ Wv^T  -> vT[b][d][t] transposed store
__global__ __launch_bounds__(256, 2) void yv_gemm(
    const __hip_bfloat16* __restrict__ xbb,
    const __hip_bfloat16* __restrict__ G,
    const __hip_bfloat16* __restrict__ Wvb,
    __hip_bfloat16* __restrict__ Yout,
    __hip_bfloat16* __restrict__ vTout)
{
    const int bid = blockIdx.x;               // 0..511
    const int xcd = bid & 7;
    const int ii  = bid >> 3;                 // 0..63
    const int rt  = (xcd << 2) | (ii & 3);    // 0..31
    const int ct  = ii >> 2;                  // 0..15

    __shared__ short lsA[2][256 * 32];        // 32 KiB
    __shared__ short lsB[2][128 * 32];        // 16 KiB

    const int tid  = threadIdx.x;
    const int wave = tid >> 6;
    const int lane = tid & 63;
    const int wr   = (wave >> 1) * 128;
    const int wc   = (wave &  1) * 64;
    const int sr   = lane >> 2;
    const int scol = ((lane & 3) ^ ((lane >> 3) & 3)) * 8;   // T2 swizzle
    const int frow = lane & 15;
    const int fk   = ((lane >> 4) ^ ((lane >> 1) & 3)) * 8;

    const short* A = (const short*)xbb + (long)rt * 256 * 1024;
    const short* B = (ct < 8)
        ? (const short*)G   + (long)ct * 128 * 1024
        : (const short*)Wvb + (long)(ct - 8) * 128 * 1024;

    f32x4 acc[8][4] = {};

    for (int k0 = 0; k0 < 1024; k0 += 64) {
        const short* ga = A + (long)(wave * 64 + sr) * 1024 + k0 + scol;
        const short* gb = B + (long)(wave * 32 + sr) * 1024 + k0 + scol;
        #pragma unroll
        for (int i = 0; i < 2; ++i) {
            load_lds16(gb + (long)i * 16384,      &lsB[0][(wave * 32 + i * 16) * 32]);
            load_lds16(gb + (long)i * 16384 + 32, &lsB[1][(wave * 32 + i * 16) * 32]);
        }
        #pragma unroll
        for (int i = 0; i < 4; ++i) {
            load_lds16(ga + (long)i * 16384,      &lsA[0][(wave * 64 + i * 16) * 32]);
            load_lds16(ga + (long)i * 16384 + 32, &lsA[1][(wave * 64 + i * 16) * 32]);
        }
        __syncthreads();

        #pragma unroll
        for (int sub = 0; sub < 2; ++sub) {
            bf16x8 af[8], bfr[4];
            #pragma unroll
            for (int m = 0; m < 8; ++m)
                af[m] = *(const bf16x8*)&lsA[sub][(wr + m * 16 + frow) * 32 + fk];
            #pragma unroll
            for (int n = 0; n < 4; ++n)
                bfr[n] = *(const bf16x8*)&lsB[sub][(wc + n * 16 + frow) * 32 + fk];
            #pragma unroll
            for (int m = 0; m < 8; ++m)
                #pragma unroll
                for (int n = 0; n < 4; ++n)
                    acc[m][n] = __builtin_amdgcn_mfma_f32_16x16x32_bf16(
                        af[m], bfr[n], acc[m][n], 0, 0, 0);
        }
        __syncthreads();
    }

    const long crow0 = (long)rt * 256 + wr;
    const int  orow  = (lane >> 4) * 4;
    const int  ocol  = lane & 15;

    if (ct >= 8) {                            // V: transposed into vT[b][d][t]
        const long dcol0 = (long)(ct - 8) * 128 + wc;
        #pragma unroll
        for (int m = 0; m < 8; ++m) {
            const long rowb = crow0 + m * 16 + orow;   // multiple of 4
            const long b    = rowb >> 11;
            const long t0   = rowb & 2047;
            #pragma unroll
            for (int n = 0; n < 4; ++n) {
                const long d = dcol0 + n * 16 + ocol;
                bh4 pk = pack4(acc[m][n][0], acc[m][n][1],
                               acc[m][n][2], acc[m][n][3]);
                *(bh4*)&vTout[((b << 10) + d) * 2048 + t0] = pk;
            }
        }
    } else {                                  // Y: plain row store, ldc=1024
        const long ccol0 = (long)ct * 128 + wc;
        #pragma unroll
        for (int m = 0; m < 8; ++m)
            #pragma unroll
            for (int n = 0; n < 4; ++n)
                #pragma unroll
                for (int r = 0; r < 4; ++r)
                    Yout[(crow0 + m * 16 + orow + r) * 1024 +
                         ccol0 + n * 16 + ocol] =
                        __float2bfloat16(acc[m][n][r]);
    }
}

// ================================================================ S core
// S = Y @ xb^T (K gone). Thin 128x128, 544 blocks, 3/CU. XCD triangle.
__device__ __constant__ int S_RT0[8] = {12, 13, 14, 15, 0, 1, 2, 3};
__device__ __constant__ int S_RT1[8] = {8, 9, 10, 11, 4, 5, 6, 7};

__global__ __launch_bounds__(256, 3) void s_gemm(
    const __hip_bfloat16* __restrict__ Y,
    const __hip_bfloat16* __restrict__ xbb,
    __hip_bfloat16* __restrict__ P,
    float* __restrict__ Lbuf)
{
    const int bid = blockIdx.x;               // 0..543
    const int xcd = bid & 7;
    const int bz  = xcd >> 1;
    const int* rts = (xcd & 1) ? S_RT1 : S_RT0;
    int idx = bid >> 3;                       // 0..67
    int seg = 0;
    while (idx >= rts[seg] + 1) { idx -= rts[seg] + 1; ++seg; }
    const int rt = rts[seg];
    const int ct = idx;

    __shared__ short lsA[2][128 * 32];
    __shared__ short lsB[2][128 * 32];

    const int tid  = threadIdx.x;
    const int wave = tid >> 6;
    const int lane = tid & 63;
    const int wr   = (wave >> 1) * 64;
    const int wc   = (wave &  1) * 64;
    const int srow = wave * 32 + (lane >> 2);
    const int scol = ((lane & 3) ^ ((lane >> 3) & 3)) * 8;   // T2 swizzle
    const int frow = lane & 15;
    const int fk   = ((lane >> 4) ^ ((lane >> 1) & 3)) * 8;

    const short* A = (const short*)Y   + (long)bz * 2097152 + (long)rt * 128 * 1024;
    const short* B = (const short*)xbb + (long)bz * 2097152 + (long)ct * 128 * 1024;

    f32x4 acc[4][4] = {};

    for (int k0 = 0; k0 < 1024; k0 += 64) {
        const short* ga = A + (long)srow * 1024 + k0 + scol;
        const short* gb = B + (long)srow * 1024 + k0 + scol;
        load_lds16(gb,                   &lsB[0][(wave * 32) * 32]);
        load_lds16(gb + 16384,           &lsB[0][(wave * 32 + 16) * 32]);
        load_lds16(gb + 32,              &lsB[1][(wave * 32) * 32]);
        load_lds16(gb + 16384 + 32,      &lsB[1][(wave * 32 + 16) * 32]);
        load_lds16(ga,                   &lsA[0][(wave * 32) * 32]);
        load_lds16(ga + 16384,           &lsA[0][(wave * 32 + 16) * 32]);
        load_lds16(ga + 32,              &lsA[1][(wave * 32) * 32]);
        load_lds16(ga + 16384 + 32,      &lsA[1][(wave * 32 + 16) * 32]);
        __syncthreads();

        #pragma unroll
        for (int sub = 0; sub < 2; ++sub) {
            bf16x8 af[4], bfr[4];
            #pragma unroll
            for (int m = 0; m < 4; ++m)
                af[m] = *(const bf16x8*)&lsA[sub][(wr + m * 16 + frow) * 32 + fk];
            #pragma unroll
            for (int n = 0; n < 4; ++n)
                bfr[n] = *(const bf16x8*)&lsB[sub][(wc + n * 16 + frow) * 32 + fk];
            #pragma unroll
            for (int m = 0; m < 4; ++m)
                #pragma unroll
                for (int n = 0; n < 4; ++n)
                    acc[m][n] = __builtin_amdgcn_mfma_f32_16x16x32_bf16(
                        af[m], bfr[n], acc[m][n], 0, 0, 0);
        }
        __syncthreads();
    }

    // epilogue: exp(s/32) masked + scalar per-(m,r) rowsum
    const long crow0 = (long)rt * 128 + wr;
    const long ccol0 = (long)ct * 128 + wc;
    const int  orow  = (lane >> 4) * 4;
    const int  ocol  = lane & 15;
    __hip_bfloat16* C = P + (long)bz * 4194304;

    #pragma unroll
    for (int m = 0; m < 4; ++m)
        #pragma unroll
        for (int r = 0; r < 4; ++r) {
            const long row = crow0 + m * 16 + orow + r;
            float sum = 0.f;
            #pragma unroll
            for (int n = 0; n < 4; ++n) {
                const long col = ccol0 + n * 16 + ocol;
                float p = (col <= row) ? __expf(acc[m][n][r] * 0.03125f) : 0.f;
                C[row * 2048 + col] = __float2bfloat16(p);
                sum += p;
            }
            sum += __shfl_xor(sum, 1);
            sum += __shfl_xor(sum, 2);
            sum += __shfl_xor(sum, 4);
            sum += __shfl_xor(sum, 8);
            if ((lane & 15) == 0)
                atomicAdd(&Lbuf[bz * T_SEQ + row], sum);
        }
}

// ---------------------------------------------------------------- PV split-K
// 768 blocks = 8 XCD-groups x 96. xcd -> (bz = xcd>>1, half = xcd&1).
// Balanced p-remap: a = idx>>5, c = idx&31, ct = c&7,
//   p = a==0 ? c>>3 : a==1 ? 7-(c>>3) : 8+(c>>3).
// half0 p<8: direct rt=p, full K, rows<1024 -> plain scaled store.
// All other paths are 2-writer split rows >=1024 -> scaled atomicAdd into
// pre-zeroed d_out (exactly 2 commutative fp32 adds per element).
__global__ __launch_bounds__(256, 3) void pv_split(
    const __hip_bfloat16* __restrict__ P,
    const __hip_bfloat16* __restrict__ Vt,
    float* __restrict__ out,
    const float* __restrict__ Lbuf)
{
    const int bid  = blockIdx.x;             // 0..767
    const int xcd  = bid & 7;
    const int bz   = xcd >> 1;
    const int half = xcd & 1;
    const int idx  = bid >> 3;               // 0..95
    const int a    = idx >> 5;               // 0..2
    const int c    = idx & 31;
    const int ct   = c & 7;
    const int p    = (a == 0) ? (c >> 3) : (a == 1) ? (7 - (c >> 3)) : (8 + (c >> 3));

    int rt, k0s, k0e;
    bool direct = false;
    if (half == 0) {
        if (p < 8) { rt = p; k0s = 0; k0e = (rt + 1) * 128; direct = true; }
        else       { rt = p; k0s = 0; k0e = 1024; }              // rt 8..11 low-K
    } else {
        if (p < 4) { rt = 12 + p; k0s = 0; k0e = 1024; }         // rt 12..15 low-K
        else       { rt = 4 + p;  k0s = 1024; k0e = (rt + 1) * 128; }  // high-K
    }
    float* dst = out + (long)bz * 2097152 + (long)rt * 128 * 1024;

    __shared__ short lsA[2][128 * 32];
    __shared__ short lsB[2][128 * 32];

    const int tid  = threadIdx.x;
    const int wave = tid >> 6;
    const int lane = tid & 63;
    const int wr   = (wave >> 1) * 64;
    const int wc   = (wave &  1) * 64;
    const int srow = wave * 32 + (lane >> 2);
    const int scol = ((lane & 3) ^ ((lane >> 3) & 3)) * 8;   // T2 swizzle
    const int frow = lane & 15;
    const int fk   = ((lane >> 4) ^ ((lane >> 1) & 3)) * 8;

    const short* A = (const short*)P  + (long)bz * 4194304 + (long)rt * 128 * 2048;
    const short* B = (const short*)Vt + (long)bz * 2097152 + (long)ct * 128 * 2048;

    f32x4 acc[4][4] = {};

    for (int k0 = k0s; k0 < k0e; k0 += 64) {
        const short* ga = A + (long)srow * 2048 + k0 + scol;
        const short* gb = B + (long)srow * 2048 + k0 + scol;
        load_lds16(gb,                   &lsB[0][(wave * 32) * 32]);
        load_lds16(gb + 16L * 2048,      &lsB[0][(wave * 32 + 16) * 32]);
        load_lds16(gb + 32,              &lsB[1][(wave * 32) * 32]);
        load_lds16(gb + 16L * 2048 + 32, &lsB[1][(wave * 32 + 16) * 32]);
        load_lds16(ga,                   &lsA[0][(wave * 32) * 32]);
        load_lds16(ga + 16L * 2048,      &lsA[0][(wave * 32 + 16) * 32]);
        load_lds16(ga + 32,              &lsA[1][(wave * 32) * 32]);
        load_lds16(ga + 16L * 2048 + 32, &lsA[1][(wave * 32 + 16) * 32]);
        __syncthreads();

        #pragma unroll
        for (int sub = 0; sub < 2; ++sub) {
            bf16x8 af[4], bfr[4];
            #pragma unroll
            for (int m = 0; m < 4; ++m)
                af[m] = *(const bf16x8*)&lsA[sub][(wr + m * 16 + frow) * 32 + fk];
            #pragma unroll
            for (int n = 0; n < 4; ++n)
                bfr[n] = *(const bf16x8*)&lsB[sub][(wc + n * 16 + frow) * 32 + fk];
            #pragma unroll
            for (int m = 0; m < 4; ++m)
                #pragma unroll
                for (int n = 0; n < 4; ++n)
                    acc[m][n] = __builtin_amdgcn_mfma_f32_16x16x32_bf16(
                        af[m], bfr[n], acc[m][n], 0, 0, 0);
        }
        __syncthreads();
    }

    const int orow = (lane >> 4) * 4;
    const int ocol = lane & 15;
    const float* il = Lbuf + bz * T_SEQ + (long)rt * 128;
    #pragma unroll
    for (int m = 0; m < 4; ++m)
        #pragma unroll
        for (int r = 0; r < 4; ++r) {
            const long lrow = wr + m * 16 + orow + r;
            const float s = 1.f / il[lrow];
            #pragma unroll
            for (int n = 0; n < 4; ++n) {
                const long off = lrow * 1024 + ct * 128 + wc + n * 16 + ocol;
                const float v = acc[m][n][r] * s;
                if (direct) dst[off] = v;
                else        atomicAdd(&dst[off], v);
            }
        }
}

// ---------------------------------------------------------------- launch
extern "C" void kernel_launch(void* const* d_in, const int* in_sizes, int n_in,
                              void* d_out, int out_size, void* d_ws, size_t ws_size,
                              hipStream_t stream) {
    const float* x  = (const float*)d_in[0];
    const float* Wq = (const float*)d_in[1];
    const float* Wk = (const float*)d_in[2];
    const float* Wv = (const float*)d_in[3];

    char* ws = (char*)d_ws;
    // workspace (bytes):
    //   xb   @ 0         : 16,777,216  (alive through s_gemm)
    //   wqt  @ 16777216  :  2,097,152
    //   wkt  @ 18874368  :  2,097,152
    //   wvb  @ 20971520  :  2,097,152
    //   Y    @ 23068672  : 16,777,216
    //   G    @ 39845888  :  2,097,152
    //   vT   @ 73400320  : 16,777,216
    //   P    @ 90177536  : 33,554,432
    //   l    @ 123731968 :     32,768
    __hip_bfloat16* xb   = (__hip_bfloat16*)(ws);
    __hip_bfloat16* wqt  = (__hip_bfloat16*)(ws + 16777216);
    __hip_bfloat16* wkt  = (__hip_bfloat16*)(ws + 18874368);
    __hip_bfloat16* wvb  = (__hip_bfloat16*)(ws + 20971520);
    __hip_bfloat16* Y    = (__hip_bfloat16*)(ws + 23068672);
    __hip_bfloat16* G    = (__hip_bfloat16*)(ws + 39845888);
    __hip_bfloat16* vT   = (__hip_bfloat16*)(ws + 73400320);
    __hip_bfloat16* P    = (__hip_bfloat16*)(ws + 90177536);
    float*          Lbuf = (float*)        (ws + 123731968);

    // 1) casts (x, Wv, WqT, WkT) + Lbuf zero + d_out rows>=1024 zero
    cast_all<<<dim3(13856), 256, 0, stream>>>(
        x, Wq, Wk, Wv, xb, wqt, wkt, wvb, Lbuf, (float*)d_out);

    // 2) G = Wk^T Wq  (thin core, 64 blocks)
    g_gemm<<<dim3(64), 256, 0, stream>>>(wkt, wqt, G);

    // 3) Y = xb @ G^T  and  V -> vT (fat core, 512 blocks = 1 round)
    yv_gemm<<<dim3(512), 256, 0, stream>>>(xb, G, wvb, Y, vT);

    // 4) P = exp(mask(Y xb^T)/32) bf16 + atomic rowsums (thin, 544 blocks)
    s_gemm<<<dim3(544), 256, 0, stream>>>(Y, xb, P, Lbuf);

    // 5) O = P @ V ; balanced split-K, scaled atomicAdd combine (no finish)
    pv_split<<<dim3(768), 256, 0, stream>>>(
        P, vT, (float*)d_out, Lbuf);
}

// Round 12
// 204.928 us; speedup vs baseline: 1.0774x; 1.0774x over previous
//
#include <hip/hip_runtime.h>
#include <hip/hip_bf16.h>

// B=4, T=2048, C=1024 single-head causal attention, fp32 in/out.
// R18 = R16 revert (best measured: 207.0), resubmitted after an infra
// failure (container never ran). R17's algebraic restructure regressed:
// the 1-round yv grid lost backfill TLP (710 vs 930 TF) and g_gemm added
// an idle-machine launch. Components here are all individually measured:
// fat qkv (930 TF, B-first staging), thin-S 544 blocks @ ~3/CU, balanced
// pv split-K, pv_finish.

typedef short bf16x8 __attribute__((ext_vector_type(8)));
typedef float f32x4  __attribute__((ext_vector_type(4)));

#define T_SEQ 2048
#define EMB   1024
#define NBAT  4

struct alignas(8) bh4 { __hip_bfloat16 a, b, c, d; };

__device__ __forceinline__ bh4 pack4(float x, float y, float z, float w) {
    bh4 o { __float2bfloat16(x), __float2bfloat16(y),
            __float2bfloat16(z), __float2bfloat16(w) };
    return o;
}

// ---------------------------------------------------------------- merged cast
__global__ void cast_all(const float* __restrict__ x,
                         const float* __restrict__ w0,
                         const float* __restrict__ w1,
                         const float* __restrict__ w2,
                         __hip_bfloat16* __restrict__ xb,
                         __hip_bfloat16* __restrict__ wb,
                         float* __restrict__ Lbuf) {
    const int bid = blockIdx.x;
    if (bid < 8192) {
        int i = bid * 256 + threadIdx.x;
        float4 v = reinterpret_cast<const float4*>(x)[i];
        reinterpret_cast<bh4*>(xb)[i] = pack4(v.x, v.y, v.z, v.w);
    } else if (bid < 11264) {
        int j = bid - 8192;                       // 0..3071
        int sel = j >> 10;
        const float* src = (sel == 0) ? w0 : (sel == 1) ? w1 : w2;
        int i = (j & 1023) * 256 + threadIdx.x;
        float4 v = reinterpret_cast<const float4*>(src)[i];
        reinterpret_cast<bh4*>(wb + (size_t)sel * 1048576)[i] =
            pack4(v.x, v.y, v.z, v.w);
    } else {
        Lbuf[(bid - 11264) * 256 + threadIdx.x] = 0.f;
    }
}

// ---------------------------------------------------------------- helpers
__device__ __forceinline__ void load_lds16(const void* g, void* l) {
    __builtin_amdgcn_global_load_lds(
        (const __attribute__((address_space(1))) void*)g,
        (__attribute__((address_space(3))) void*)l, 16, 0, 0);
}

// ================================================================ QKV core
// C = A[8192,1024] * B[3072,1024]^T. Block 256x128, 4 waves, wave 128x64.
// Q/K cols -> qkv rows; V cols (ct>=16) -> vT[b][d][t] transposed.
__global__ __launch_bounds__(256, 2) void qkv_gemm(
    const __hip_bfloat16* __restrict__ Abase,
    const __hip_bfloat16* __restrict__ Bbase,
    __hip_bfloat16* __restrict__ qkvOut,
    __hip_bfloat16* __restrict__ vTout)
{
    const int bid = blockIdx.x;               // 0..767 (768 = 8 XCD x 96)
    const int xcd = bid & 7;
    const int ii  = bid >> 3;                 // 0..95
    const int rt  = (xcd << 2) | (ii & 3);    // 0..31 (rows of 256)
    const int ct  = ii >> 2;                  // 0..23 (cols of 128)

    __shared__ short lsA[2][256 * 32];        // 32 KiB
    __shared__ short lsB[2][128 * 32];        // 16 KiB

    const int tid  = threadIdx.x;
    const int wave = tid >> 6;
    const int lane = tid & 63;
    const int wr   = (wave >> 1) * 128;       // wave row base in tile
    const int wc   = (wave &  1) * 64;        // wave col base in tile
    const int sr   = lane >> 2;               // staging row 0..15
    // T2 swizzle (all row-base offsets are 0 mod 16 so they drop out):
    const int scol = ((lane & 3) ^ ((lane >> 3) & 3)) * 8;
    const int frow = lane & 15;
    const int fk   = ((lane >> 4) ^ ((lane >> 1) & 3)) * 8;

    const short* A = (const short*)Abase + (long)rt * 256 * 1024;
    const short* B = (const short*)Bbase + (long)ct * 128 * 1024;

    f32x4 acc[8][4] = {};

    for (int k0 = 0; k0 < 1024; k0 += 64) {
        const short* ga = A + (long)(wave * 64 + sr) * 1024 + k0 + scol;
        const short* gb = B + (long)(wave * 32 + sr) * 1024 + k0 + scol;
        // B (W-panel, L3-latency) first so its latency leads the drain.
        #pragma unroll
        for (int i = 0; i < 2; ++i) {
            load_lds16(gb + (long)i * 16384,      &lsB[0][(wave * 32 + i * 16) * 32]);
            load_lds16(gb + (long)i * 16384 + 32, &lsB[1][(wave * 32 + i * 16) * 32]);
        }
        #pragma unroll
        for (int i = 0; i < 4; ++i) {
            load_lds16(ga + (long)i * 16384,      &lsA[0][(wave * 64 + i * 16) * 32]);
            load_lds16(ga + (long)i * 16384 + 32, &lsA[1][(wave * 64 + i * 16) * 32]);
        }
        __syncthreads();

        #pragma unroll
        for (int sub = 0; sub < 2; ++sub) {
            bf16x8 af[8], bfr[4];
            #pragma unroll
            for (int m = 0; m < 8; ++m)
                af[m] = *(const bf16x8*)&lsA[sub][(wr + m * 16 + frow) * 32 + fk];
            #pragma unroll
            for (int n = 0; n < 4; ++n)
                bfr[n] = *(const bf16x8*)&lsB[sub][(wc + n * 16 + frow) * 32 + fk];
            #pragma unroll
            for (int m = 0; m < 8; ++m)
                #pragma unroll
                for (int n = 0; n < 4; ++n)
                    acc[m][n] = __builtin_amdgcn_mfma_f32_16x16x32_bf16(
                        af[m], bfr[n], acc[m][n], 0, 0, 0);
        }
        __syncthreads();
    }

    // epilogue: C/D layout col = lane&15, row = (lane>>4)*4 + reg
    const long crow0 = (long)rt * 256 + wr;
    const long ccol0 = (long)ct * 128 + wc;
    const int  orow  = (lane >> 4) * 4;
    const int  ocol  = lane & 15;

    if (ct >= 16) {
        // V columns: store transposed into vT[b][d][t] (d = col-2048).
        #pragma unroll
        for (int m = 0; m < 8; ++m) {
            const long rowb = crow0 + m * 16 + orow;   // multiple of 4
            const long b    = rowb >> 11;
            const long t0   = rowb & 2047;
            #pragma unroll
            for (int n = 0; n < 4; ++n) {
                const long d = ccol0 + n * 16 + ocol - 2048;
                bh4 pk = pack4(acc[m][n][0], acc[m][n][1],
                               acc[m][n][2], acc[m][n][3]);
                *(bh4*)&vTout[((b << 10) + d) * 2048 + t0] = pk;
            }
        }
    } else {                                  // Q/K columns: plain row store
        #pragma unroll
        for (int m = 0; m < 8; ++m)
            #pragma unroll
            for (int n = 0; n < 4; ++n)
                #pragma unroll
                for (int r = 0; r < 4; ++r)
                    qkvOut[(crow0 + m * 16 + orow + r) * 3072 +
                           ccol0 + n * 16 + ocol] =
                        __float2bfloat16(acc[m][n][r]);
    }
}

// ================================================================ S core
// Thin 128x128 core, 544 blocks, 3 blocks/CU. XCD-grouped triangle:
// half0 rts {12..15, 0..3}, half1 {8..11, 4..7}; counts rt+1 (68/XCD).
__device__ __constant__ int S_RT0[8] = {12, 13, 14, 15, 0, 1, 2, 3};
__device__ __constant__ int S_RT1[8] = {8, 9, 10, 11, 4, 5, 6, 7};

__global__ __launch_bounds__(256, 3) void s_gemm(
    const __hip_bfloat16* __restrict__ QKV,
    __hip_bfloat16* __restrict__ P,
    float* __restrict__ Lbuf)
{
    const int bid = blockIdx.x;               // 0..543
    const int xcd = bid & 7;
    const int bz  = xcd >> 1;
    const int* rts = (xcd & 1) ? S_RT1 : S_RT0;
    int idx = bid >> 3;                       // 0..67
    int seg = 0;
    while (idx >= rts[seg] + 1) { idx -= rts[seg] + 1; ++seg; }
    const int rt = rts[seg];
    const int ct = idx;

    __shared__ short lsA[2][128 * 32];
    __shared__ short lsB[2][128 * 32];

    const int tid  = threadIdx.x;
    const int wave = tid >> 6;
    const int lane = tid & 63;
    const int wr   = (wave >> 1) * 64;
    const int wc   = (wave &  1) * 64;
    const int srow = wave * 32 + (lane >> 2);
    const int scol = ((lane & 3) ^ ((lane >> 3) & 3)) * 8;   // T2 swizzle
    const int frow = lane & 15;
    const int fk   = ((lane >> 4) ^ ((lane >> 1) & 3)) * 8;

    const short* A = (const short*)QKV + (long)bz * 6291456
                   + (long)rt * 128 * 3072;            // Q rows
    const short* B = (const short*)QKV + (long)bz * 6291456 + 1024
                   + (long)ct * 128 * 3072;            // K rows

    f32x4 acc[4][4] = {};

    for (int k0 = 0; k0 < 1024; k0 += 64) {
        const short* ga = A + (long)srow * 3072 + k0 + scol;
        const short* gb = B + (long)srow * 3072 + k0 + scol;
        load_lds16(gb,                   &lsB[0][(wave * 32) * 32]);
        load_lds16(gb + 16L * 3072,      &lsB[0][(wave * 32 + 16) * 32]);
        load_lds16(gb + 32,              &lsB[1][(wave * 32) * 32]);
        load_lds16(gb + 16L * 3072 + 32, &lsB[1][(wave * 32 + 16) * 32]);
        load_lds16(ga,                   &lsA[0][(wave * 32) * 32]);
        load_lds16(ga + 16L * 3072,      &lsA[0][(wave * 32 + 16) * 32]);
        load_lds16(ga + 32,              &lsA[1][(wave * 32) * 32]);
        load_lds16(ga + 16L * 3072 + 32, &lsA[1][(wave * 32 + 16) * 32]);
        __syncthreads();

        #pragma unroll
        for (int sub = 0; sub < 2; ++sub) {
            bf16x8 af[4], bfr[4];
            #pragma unroll
            for (int m = 0; m < 4; ++m)
                af[m] = *(const bf16x8*)&lsA[sub][(wr + m * 16 + frow) * 32 + fk];
            #pragma unroll
            for (int n = 0; n < 4; ++n)
                bfr[n] = *(const bf16x8*)&lsB[sub][(wc + n * 16 + frow) * 32 + fk];
            #pragma unroll
            for (int m = 0; m < 4; ++m)
                #pragma unroll
                for (int n = 0; n < 4; ++n)
                    acc[m][n] = __builtin_amdgcn_mfma_f32_16x16x32_bf16(
                        af[m], bfr[n], acc[m][n], 0, 0, 0);
        }
        __syncthreads();
    }

    // epilogue: exp(s/32) masked + scalar per-(m,r) rowsum (low VGPR)
    const long crow0 = (long)rt * 128 + wr;
    const long ccol0 = (long)ct * 128 + wc;
    const int  orow  = (lane >> 4) * 4;
    const int  ocol  = lane & 15;
    __hip_bfloat16* C = P + (long)bz * 4194304;

    #pragma unroll
    for (int m = 0; m < 4; ++m)
        #pragma unroll
        for (int r = 0; r < 4; ++r) {
            const long row = crow0 + m * 16 + orow + r;
            float sum = 0.f;
            #pragma unroll
            for (int n = 0; n < 4; ++n) {
                const long col = ccol0 + n * 16 + ocol;
                float p = (col <= row) ? __expf(acc[m][n][r] * 0.03125f) : 0.f;
                C[row * 2048 + col] = __float2bfloat16(p);
                sum += p;
            }
            sum += __shfl_xor(sum, 1);
            sum += __shfl_xor(sum, 2);
            sum += __shfl_xor(sum, 4);
            sum += __shfl_xor(sum, 8);
            if ((lane & 15) == 0)
                atomicAdd(&Lbuf[bz * T_SEQ + row], sum);
        }
}

// ---------------------------------------------------------------- PV split-K
// 768 blocks = 8 XCD-groups x 96. xcd -> (bz = xcd>>1, half = xcd&1).
// Balanced p-remap: a = idx>>5, c = idx&31, ct = c&7,
//   p = a==0 ? c>>3 : a==1 ? 7-(c>>3) : 8+(c>>3)
// -> every in-order dispatch triple {a=0,1,2} sums to exactly 17 units.
// half0: p<8  -> direct rt=p, full K, scaled -> d_out  (vT t<1024 only)
//        p>=8 -> part0 rt=p (8..11), K tiles [0,8)     -> d_out unscaled
// half1: p<4  -> part0 rt=12+p, K tiles [0,8)          -> d_out unscaled
//        p>=4 -> part1 rt=8+(p-4)=4+p, K [1024,(rt+1)*128) -> tmp1
// pv_finish combines rows >= 1024.
__global__ __launch_bounds__(256, 3) void pv_split(
    const __hip_bfloat16* __restrict__ P,
    const __hip_bfloat16* __restrict__ Vt,
    float* __restrict__ out,
    float* __restrict__ tmp1,
    const float* __restrict__ Lbuf)
{
    const int bid  = blockIdx.x;             // 0..767
    const int xcd  = bid & 7;
    const int bz   = xcd >> 1;
    const int half = xcd & 1;
    const int idx  = bid >> 3;               // 0..95
    const int a    = idx >> 5;               // 0..2
    const int c    = idx & 31;
    const int ct   = c & 7;
    const int p    = (a == 0) ? (c >> 3) : (a == 1) ? (7 - (c >> 3)) : (8 + (c >> 3));

    int rt, k0s, k0e;
    bool scaled = false;
    float* dst;
    if (half == 0) {
        if (p < 8) {
            rt = p; k0s = 0; k0e = (rt + 1) * 128; scaled = true;
            dst = out + (long)bz * 2097152 + (long)rt * 128 * 1024;
        } else {
            rt = p;  // 8..11
            k0s = 0; k0e = 1024;
            dst = out + (long)bz * 2097152 + (long)rt * 128 * 1024;
        }
    } else {
        if (p < 4) {
            rt = 12 + p; k0s = 0; k0e = 1024;
            dst = out + (long)bz * 2097152 + (long)rt * 128 * 1024;
        } else {
            rt = 4 + p;  // 8..15
            k0s = 1024; k0e = (rt + 1) * 128;
            dst = tmp1 + ((long)bz * 1024 + (long)(rt - 8) * 128) * 1024;
        }
    }

    __shared__ short lsA[2][128 * 32];
    __shared__ short lsB[2][128 * 32];

    const int tid  = threadIdx.x;
    const int wave = tid >> 6;
    const int lane = tid & 63;
    const int wr   = (wave >> 1) * 64;
    const int wc   = (wave &  1) * 64;
    const int srow = wave * 32 + (lane >> 2);
    const int scol = ((lane & 3) ^ ((lane >> 3) & 3)) * 8;   // T2 swizzle
    const int frow = lane & 15;
    const int fk   = ((lane >> 4) ^ ((lane >> 1) & 3)) * 8;

    const short* A = (const short*)P  + (long)bz * 4194304 + (long)rt * 128 * 2048;
    const short* B = (const short*)Vt + (long)bz * 2097152 + (long)ct * 128 * 2048;

    f32x4 acc[4][4] = {};

    for (int k0 = k0s; k0 < k0e; k0 += 64) {
        const short* ga = A + (long)srow * 2048 + k0 + scol;
        const short* gb = B + (long)srow * 2048 + k0 + scol;
        load_lds16(gb,                   &lsB[0][(wave * 32) * 32]);
        load_lds16(gb + 16L * 2048,      &lsB[0][(wave * 32 + 16) * 32]);
        load_lds16(gb + 32,              &lsB[1][(wave * 32) * 32]);
        load_lds16(gb + 16L * 2048 + 32, &lsB[1][(wave * 32 + 16) * 32]);
        load_lds16(ga,                   &lsA[0][(wave * 32) * 32]);
        load_lds16(ga + 16L * 2048,      &lsA[0][(wave * 32 + 16) * 32]);
        load_lds16(ga + 32,              &lsA[1][(wave * 32) * 32]);
        load_lds16(ga + 16L * 2048 + 32, &lsA[1][(wave * 32 + 16) * 32]);
        __syncthreads();

        #pragma unroll
        for (int sub = 0; sub < 2; ++sub) {
            bf16x8 af[4], bfr[4];
            #pragma unroll
            for (int m = 0; m < 4; ++m)
                af[m] = *(const bf16x8*)&lsA[sub][(wr + m * 16 + frow) * 32 + fk];
            #pragma unroll
            for (int n = 0; n < 4; ++n)
                bfr[n] = *(const bf16x8*)&lsB[sub][(wc + n * 16 + frow) * 32 + fk];
            #pragma unroll
            for (int m = 0; m < 4; ++m)
                #pragma unroll
                for (int n = 0; n < 4; ++n)
                    acc[m][n] = __builtin_amdgcn_mfma_f32_16x16x32_bf16(
                        af[m], bfr[n], acc[m][n], 0, 0, 0);
        }
        __syncthreads();
    }

    const int orow = (lane >> 4) * 4;
    const int ocol = lane & 15;
    if (scaled) {
        const float* il = Lbuf + bz * T_SEQ + (long)rt * 128;
        #pragma unroll
        for (int m = 0; m < 4; ++m)
            #pragma unroll
            for (int r = 0; r < 4; ++r) {
                const long lrow = wr + m * 16 + orow + r;
                const float s = 1.f / il[lrow];
                #pragma unroll
                for (int n = 0; n < 4; ++n)
                    dst[lrow * 1024 + ct * 128 + wc + n * 16 + ocol] =
                        acc[m][n][r] * s;
            }
    } else {
        #pragma unroll
        for (int m = 0; m < 4; ++m)
            #pragma unroll
            for (int r = 0; r < 4; ++r) {
                const long lrow = wr + m * 16 + orow + r;
                #pragma unroll
                for (int n = 0; n < 4; ++n)
                    dst[lrow * 1024 + ct * 128 + wc + n * 16 + ocol] = acc[m][n][r];
            }
    }
}

// ---------------------------------------------------------------- PV finish
// rows >= 1024 per batch: out = (out + tmp1) / l.
__global__ void pv_finish(float* __restrict__ out,
                          const float* __restrict__ tmp1,
                          const float* __restrict__ Lbuf) {
    const int g = blockIdx.x;                // 0..4095
    const int b = g >> 10;
    const int r = (g & 1023) + 1024;
    const int c = threadIdx.x * 4;
    const float s = 1.f / Lbuf[b * T_SEQ + r];
    float* po = out + (long)b * 2097152 + (long)r * 1024 + c;
    float4 o = *(const float4*)po;
    float4 t = *(const float4*)&tmp1[((long)b * 1024 + (r - 1024)) * 1024 + c];
    o.x = (o.x + t.x) * s; o.y = (o.y + t.y) * s;
    o.z = (o.z + t.z) * s; o.w = (o.w + t.w) * s;
    *(float4*)po = o;
}

// ---------------------------------------------------------------- launch
extern "C" void kernel_launch(void* const* d_in, const int* in_sizes, int n_in,
                              void* d_out, int out_size, void* d_ws, size_t ws_size,
                              hipStream_t stream) {
    const float* x  = (const float*)d_in[0];
    const float* Wq = (const float*)d_in[1];
    const float* Wk = (const float*)d_in[2];
    const float* Wv = (const float*)d_in[3];

    char* ws = (char*)d_ws;
    // workspace (bytes):
    //   xb   @ 0         : 16,777,216   (dead after QKV; tmp1 aliases)
    //   wb   @ 16777216  :  6,291,456
    //   qkv  @ 23068672  : 50,331,648   (Q|K cols used; V cols unwritten)
    //   vT   @ 73400320  : 16,777,216
    //   P    @ 90177536  : 33,554,432
    //   l    @ 123731968 :     32,768
    __hip_bfloat16* xb   = (__hip_bfloat16*)(ws);
    __hip_bfloat16* wb   = (__hip_bfloat16*)(ws + 16777216);
    __hip_bfloat16* qkv  = (__hip_bfloat16*)(ws + 23068672);
    __hip_bfloat16* vT   = (__hip_bfloat16*)(ws + 73400320);
    __hip_bfloat16* P    = (__hip_bfloat16*)(ws + 90177536);
    float*          Lbuf = (float*)        (ws + 123731968);
    float*          tmp1 = (float*)        (ws);              // aliases xb

    // 1) casts + Lbuf zero
    cast_all<<<dim3(11296), 256, 0, stream>>>(x, Wq, Wk, Wv, xb, wb, Lbuf);

    // 2) fused QKV; fat-wave 256x128 core. Q/K -> qkv, V -> vT transposed
    qkv_gemm<<<dim3(768), 256, 0, stream>>>(xb, wb, qkv, vT);

    // 3) P = exp(mask(QK^T)/32) bf16 + atomic rowsums; thin core, 3/CU
    s_gemm<<<dim3(544), 256, 0, stream>>>(qkv, P, Lbuf);

    // 4) O = P @ V ; XCD-grouped balanced split-K
    pv_split<<<dim3(768), 256, 0, stream>>>(
        P, vT, (float*)d_out, tmp1, Lbuf);

    // 5) combine + scale split rows
    pv_finish<<<dim3(4096), 256, 0, stream>>>((float*)d_out, tmp1, Lbuf);
}